// Round 2
// baseline (167.199 us; speedup 1.0000x reference)
//
#include <hip/hip_runtime.h>
#include <hip/hip_bf16.h>

#define LEAK 0.2f

typedef __attribute__((ext_vector_type(8))) short short8;
typedef __attribute__((ext_vector_type(4))) float f32x4;

// ---------- fused prep: x->bf16 convert ++ W1,W2,T transpose+convert ----------
// grid: [0,6144) convert, [6144,7680) W1t, [7680,7808) W2t, [7808,7840) Tt
__global__ __launch_bounds__(256) void k_prep(const float* __restrict__ x,
                                              __hip_bfloat16* __restrict__ xb,
                                              const float* __restrict__ W1,
                                              __hip_bfloat16* __restrict__ W1t,
                                              const float* __restrict__ W2,
                                              __hip_bfloat16* __restrict__ W2t,
                                              const float* __restrict__ T,
                                              __hip_bfloat16* __restrict__ Tt) {
  int b = blockIdx.x;
  int t = threadIdx.x;
  if (b < 6144) {
    int idx = b * 256 + t;
    float4 v = reinterpret_cast<const float4*>(x)[idx];
    union { ushort4 u; __hip_bfloat16 h[4]; } c;
    c.h[0] = __float2bfloat16(v.x);
    c.h[1] = __float2bfloat16(v.y);
    c.h[2] = __float2bfloat16(v.z);
    c.h[3] = __float2bfloat16(v.w);
    reinterpret_cast<ushort4*>(xb)[idx] = c.u;
    return;
  }
  __shared__ float tile[32][33];
  const float* W;
  __hip_bfloat16* Wt;
  int K, N, kblk, nblk;
  int b2 = b - 6144;
  if (b2 < 1536) {                  // W1: 3072x512 -> 512x3072
    W = W1; Wt = W1t; K = 3072; N = 512;
    kblk = b2 % 96; nblk = b2 / 96;
  } else if (b2 < 1664) {           // W2: 512x256 -> 256x512
    int b3 = b2 - 1536;
    W = W2; Wt = W2t; K = 512; N = 256;
    kblk = b3 % 16; nblk = b3 / 16;
  } else {                          // T: 256x100 -> 128x256 (zero-pad n>=100)
    int b4 = b2 - 1664;
    W = T; Wt = Tt; K = 256; N = 100;
    kblk = b4 % 8; nblk = b4 / 8;
  }
  int k0 = kblk * 32, n0 = nblk * 32;
  int tx = t & 31, ty = t >> 5;  // 32 x 8
#pragma unroll
  for (int r = 0; r < 4; ++r) {
    int n = n0 + tx;
    tile[ty + r * 8][tx] = (n < N) ? W[(long)(k0 + ty + r * 8) * N + n] : 0.f;
  }
  __syncthreads();
#pragma unroll
  for (int r = 0; r < 4; ++r)
    Wt[(long)(n0 + ty + r * 8) * K + k0 + tx] = __float2bfloat16(tile[tx][ty + r * 8]);
}

// ---------- GEMM1: 128x64 block tile, BK=64, reg-staged (m93 ladder step) ----------
// A[2048][K] bf16, Bt[512][K] bf16. 4 waves 2x2 (wave tile 64x32 = 4x2 MFMA frags x2
// k-halves). Per K-iter per wave: 12 ds_read_b128 + 16 MFMA (2x the 64-tile density).
// Padded LDS (row stride 144B): writes 8 dwords/bank, reads 8 dwords/bank = conflict-free.
__global__ __launch_bounds__(256) void k_gemm1(const __hip_bfloat16* __restrict__ A,
                                               const __hip_bfloat16* __restrict__ Bt,
                                               float* __restrict__ Cp,
                                               int K, int KSPL) {
  __shared__ __align__(16) __hip_bfloat16 As[128][72];
  __shared__ __align__(16) __hip_bfloat16 Bs[64][72];
  int tid = threadIdx.x;
  int lane = tid & 63;
  int wv = tid >> 6;
  int wm = wv & 1, wn = wv >> 1;
  int quad = lane >> 4, l16 = lane & 15;
  long m0 = (long)blockIdx.x * 128, n0 = (long)blockIdx.y * 64;
  int srow = tid >> 3, scol = (tid & 7) * 8;  // 32 rows x 8 16B-chunks per pass
  int kStart = blockIdx.z * KSPL;
  const __hip_bfloat16* Ag = A + (m0 + srow) * K + kStart + scol;
  const __hip_bfloat16* Bg = Bt + (n0 + srow) * K + kStart + scol;

  int4 ra[4], rb[2];
#pragma unroll
  for (int p = 0; p < 4; ++p) ra[p] = *reinterpret_cast<const int4*>(Ag + (long)p * 32 * K);
#pragma unroll
  for (int p = 0; p < 2; ++p) rb[p] = *reinterpret_cast<const int4*>(Bg + (long)p * 32 * K);

  f32x4 acc[4][2] = {};
  for (int kb = 0; kb < KSPL; kb += 64) {
#pragma unroll
    for (int p = 0; p < 4; ++p) *reinterpret_cast<int4*>(&As[srow + p * 32][scol]) = ra[p];
#pragma unroll
    for (int p = 0; p < 2; ++p) *reinterpret_cast<int4*>(&Bs[srow + p * 32][scol]) = rb[p];
    __syncthreads();
    if (kb + 64 < KSPL) {
#pragma unroll
      for (int p = 0; p < 4; ++p)
        ra[p] = *reinterpret_cast<const int4*>(Ag + (long)p * 32 * K + kb + 64);
#pragma unroll
      for (int p = 0; p < 2; ++p)
        rb[p] = *reinterpret_cast<const int4*>(Bg + (long)p * 32 * K + kb + 64);
    }
#pragma unroll
    for (int half = 0; half < 2; ++half) {
      short8 af[4], bfr[2];
#pragma unroll
      for (int tm = 0; tm < 4; ++tm)
        af[tm] = *reinterpret_cast<const short8*>(&As[wm * 64 + tm * 16 + l16][half * 32 + quad * 8]);
#pragma unroll
      for (int tn = 0; tn < 2; ++tn)
        bfr[tn] = *reinterpret_cast<const short8*>(&Bs[wn * 32 + tn * 16 + l16][half * 32 + quad * 8]);
#pragma unroll
      for (int tm = 0; tm < 4; ++tm)
#pragma unroll
        for (int tn = 0; tn < 2; ++tn)
          acc[tm][tn] =
              __builtin_amdgcn_mfma_f32_16x16x32_bf16(af[tm], bfr[tn], acc[tm][tn], 0, 0, 0);
    }
    __syncthreads();
  }

  float* Cz = Cp + (long)blockIdx.z * 2048 * 512;
#pragma unroll
  for (int tm = 0; tm < 4; ++tm)
#pragma unroll
    for (int tn = 0; tn < 2; ++tn)
#pragma unroll
      for (int r = 0; r < 4; ++r) {
        long gm = m0 + wm * 64 + tm * 16 + quad * 4 + r;  // row = quad*4 + reg
        long gn = n0 + wn * 32 + tn * 16 + l16;           // col = lane&15
        Cz[gm * 512 + gn] = acc[tm][tn][r];
      }
}

// ---------- bf16 MFMA GEMM, split-K, BK=64 (round-0 known-good, 64x64 tile) ----------
template <bool TRANSP>
__global__ __launch_bounds__(256) void k_gemm(const __hip_bfloat16* __restrict__ A,
                                              const __hip_bfloat16* __restrict__ Bt,
                                              float* __restrict__ Cp,
                                              int M, int N, int K, int KSPL, int ldO) {
  __shared__ __align__(16) __hip_bfloat16 As[64][72];  // +8 pad (2-way max = free)
  __shared__ __align__(16) __hip_bfloat16 Bs[64][72];
  int tid = threadIdx.x;
  int lane = tid & 63;
  int wv = tid >> 6;
  int wm = wv & 1, wn = wv >> 1;
  int quad = lane >> 4, l16 = lane & 15;
  long m0 = (long)blockIdx.x * 64, n0 = (long)blockIdx.y * 64;
  int srow = tid >> 2, scol = (tid & 3) * 16;
  int kStart = blockIdx.z * KSPL;
  const __hip_bfloat16* Ag = A + (m0 + srow) * K + kStart + scol;
  const __hip_bfloat16* Bg = Bt + (n0 + srow) * K + kStart + scol;

  int4 ra0 = *reinterpret_cast<const int4*>(Ag);
  int4 ra1 = *reinterpret_cast<const int4*>(Ag + 8);
  int4 rb0 = *reinterpret_cast<const int4*>(Bg);
  int4 rb1 = *reinterpret_cast<const int4*>(Bg + 8);

  f32x4 acc[2][2] = {};
  for (int kb = 0; kb < KSPL; kb += 64) {
    *reinterpret_cast<int4*>(&As[srow][scol]) = ra0;
    *reinterpret_cast<int4*>(&As[srow][scol + 8]) = ra1;
    *reinterpret_cast<int4*>(&Bs[srow][scol]) = rb0;
    *reinterpret_cast<int4*>(&Bs[srow][scol + 8]) = rb1;
    __syncthreads();
    if (kb + 64 < KSPL) {
      ra0 = *reinterpret_cast<const int4*>(Ag + kb + 64);
      ra1 = *reinterpret_cast<const int4*>(Ag + kb + 72);
      rb0 = *reinterpret_cast<const int4*>(Bg + kb + 64);
      rb1 = *reinterpret_cast<const int4*>(Bg + kb + 72);
    }
#pragma unroll
    for (int half = 0; half < 2; ++half) {
      short8 af[2], bfr[2];
#pragma unroll
      for (int t = 0; t < 2; ++t) {
        af[t]  = *reinterpret_cast<const short8*>(&As[wm * 32 + t * 16 + l16][half * 32 + quad * 8]);
        bfr[t] = *reinterpret_cast<const short8*>(&Bs[wn * 32 + t * 16 + l16][half * 32 + quad * 8]);
      }
#pragma unroll
      for (int tm = 0; tm < 2; ++tm)
#pragma unroll
        for (int tn = 0; tn < 2; ++tn)
          acc[tm][tn] =
              __builtin_amdgcn_mfma_f32_16x16x32_bf16(af[tm], bfr[tn], acc[tm][tn], 0, 0, 0);
    }
    __syncthreads();
  }

  float* Cz = Cp + (long)blockIdx.z * M * N;
#pragma unroll
  for (int tm = 0; tm < 2; ++tm)
#pragma unroll
    for (int tn = 0; tn < 2; ++tn)
#pragma unroll
      for (int r = 0; r < 4; ++r) {
        long gm = m0 + wm * 32 + tm * 16 + quad * 4 + r;  // row = quad*4 + reg
        long gn = n0 + wn * 32 + tn * 16 + l16;           // col = lane&15
        if (TRANSP) Cz[gn * ldO + gm] = acc[tm][tn][r];
        else        Cz[gm * ldO + gn] = acc[tm][tn][r];
      }
}

// ---------- combine NZ partials + bias + leakyrelu -> bf16 (elementwise, h1) ----------
template <int NZ>
__global__ __launch_bounds__(256) void k_comb(const float* __restrict__ P,
                                              const float* __restrict__ bias,
                                              __hip_bfloat16* __restrict__ Ob,
                                              int total4, int nmask) {
  int idx = blockIdx.x * 256 + threadIdx.x;
  if (idx >= total4) return;
  float4 v = reinterpret_cast<const float4*>(P)[idx];
#pragma unroll
  for (int z = 1; z < NZ; ++z) {
    float4 a = reinterpret_cast<const float4*>(P + (long)z * total4 * 4)[idx];
    v.x += a.x; v.y += a.y; v.z += a.z; v.w += a.w;
  }
  int col = (idx * 4) & nmask;
  float4 bs = *reinterpret_cast<const float4*>(bias + col);
  v.x += bs.x; v.y += bs.y; v.z += bs.z; v.w += bs.w;
  v.x = v.x > 0.f ? v.x : LEAK * v.x;
  v.y = v.y > 0.f ? v.y : LEAK * v.y;
  v.z = v.z > 0.f ? v.z : LEAK * v.z;
  v.w = v.w > 0.f ? v.w : LEAK * v.w;
  union { ushort4 u; __hip_bfloat16 h[4]; } c;
  c.h[0] = __float2bfloat16(v.x);
  c.h[1] = __float2bfloat16(v.y);
  c.h[2] = __float2bfloat16(v.z);
  c.h[3] = __float2bfloat16(v.w);
  reinterpret_cast<ushort4*>(Ob)[idx] = c.u;
}

// ---------- h2 combine, wave-per-row: 2 partials + b2 + LReLU -> h2b bf16,
// plus fused final part 1: out[i] = h2[i,:].Wf[0:256] + bf  (feats added later) ----------
__global__ __launch_bounds__(256) void k_comb2row(const float* __restrict__ P,
                                                  const float* __restrict__ bias,
                                                  const float* __restrict__ Wf,
                                                  const float* __restrict__ bfp,
                                                  __hip_bfloat16* __restrict__ h2b,
                                                  float* __restrict__ out) {
  int wv = threadIdx.x >> 6, lane = threadIdx.x & 63;
  long i = (long)blockIdx.x * 4 + wv;
  long off = i * 256 + lane * 4;
  float4 v = *reinterpret_cast<const float4*>(P + off);
  float4 a = *reinterpret_cast<const float4*>(P + 2048L * 256 + off);
  v.x += a.x; v.y += a.y; v.z += a.z; v.w += a.w;
  float4 bs = *reinterpret_cast<const float4*>(bias + lane * 4);
  v.x += bs.x; v.y += bs.y; v.z += bs.z; v.w += bs.w;
  v.x = v.x > 0.f ? v.x : LEAK * v.x;
  v.y = v.y > 0.f ? v.y : LEAK * v.y;
  v.z = v.z > 0.f ? v.z : LEAK * v.z;
  v.w = v.w > 0.f ? v.w : LEAK * v.w;
  union { ushort4 u; __hip_bfloat16 h[4]; } c;
  c.h[0] = __float2bfloat16(v.x);
  c.h[1] = __float2bfloat16(v.y);
  c.h[2] = __float2bfloat16(v.z);
  c.h[3] = __float2bfloat16(v.w);
  reinterpret_cast<ushort4*>(h2b)[i * 64 + lane] = c.u;
  float4 wfv = *reinterpret_cast<const float4*>(Wf + lane * 4);
  float s = v.x * wfv.x + v.y * wfv.y + v.z * wfv.z + v.w * wfv.w;
#pragma unroll
  for (int d = 32; d; d >>= 1) s += __shfl_down(s, d);
  if (lane == 0) out[i] = s + bfp[0];
}

// ---------- bucketed minibatch-discrimination features, O(B) (round-0, no atomics) ----------
__global__ __launch_bounds__(1024) void k_bucketfeats(const float* __restrict__ mTz,
                                                      float* __restrict__ featsT) {
  __shared__ float sP[2048], sN[2048];
  __shared__ float Sp[2048], Sn[2048];
  __shared__ int Smeta[2048];
  __shared__ short sB[2048];
  __shared__ int cnt[256], bstart[256], bcur[256];
  __shared__ float bsP[256], bsN[256], Pbel[256], Nab[256];
  __shared__ float wred[32];
  __shared__ float sMin, sMax;
  int f = blockIdx.x;
  int t = threadIdx.x;
  int lane = t & 63, wv = t >> 6;
  const long FS = 2048L * 128;
  const float* row = mTz + (long)f * 2048;

  float m[2];
  float lmin = 3.4e38f, lmax = -3.4e38f;
#pragma unroll
  for (int r = 0; r < 2; ++r) {
    int e = t + r * 1024;
    float v = row[e] + row[FS + e] + row[2 * FS + e] + row[3 * FS + e];
    m[r] = v;
    lmin = fminf(lmin, v);
    lmax = fmaxf(lmax, v);
  }
#pragma unroll
  for (int d = 32; d; d >>= 1) {
    lmin = fminf(lmin, __shfl_down(lmin, d));
    lmax = fmaxf(lmax, __shfl_down(lmax, d));
  }
  if (lane == 0) { wred[wv] = lmin; wred[16 + wv] = lmax; }
  if (t < 256) cnt[t] = 0;
  __syncthreads();
  if (t == 0) {
    float a = wred[0], b = wred[16];
    for (int i = 1; i < 16; ++i) { a = fminf(a, wred[i]); b = fmaxf(b, wred[16 + i]); }
    sMin = a; sMax = b;
  }
  __syncthreads();
  float mn = sMin, mx = sMax;
  float rge = mx - mn;
  float scale = (rge > 1e-20f) ? 255.0f / rge : 0.f;
  float mid = 0.5f * (mn + mx);
#pragma unroll
  for (int r = 0; r < 2; ++r) {
    int e = t + r * 1024;
    float v = m[r];
    int b = (int)((v - mn) * scale);
    b = b < 255 ? b : 255;
    float arg = fminf(fmaxf(v - mid, -60.f), 60.f);
    sP[e] = __expf(arg);
    sN[e] = __expf(-arg);
    sB[e] = (short)b;
    atomicAdd(&cnt[b], 1);
  }
  __syncthreads();
  if (wv == 0) {  // exclusive prefix of cnt (4 bins/lane + wave scan)
    int b4 = lane * 4;
    int c0 = cnt[b4], c1 = cnt[b4 + 1], c2 = cnt[b4 + 2], c3 = cnt[b4 + 3];
    int tot = c0 + c1 + c2 + c3;
    int inc = tot;
#pragma unroll
    for (int d = 1; d < 64; d <<= 1) {
      int y = __shfl_up(inc, d);
      if (lane >= d) inc += y;
    }
    int run = inc - tot;
    bstart[b4] = run; bcur[b4] = run; run += c0;
    bstart[b4 + 1] = run; bcur[b4 + 1] = run; run += c1;
    bstart[b4 + 2] = run; bcur[b4 + 2] = run; run += c2;
    bstart[b4 + 3] = run; bcur[b4 + 3] = run;
  }
  __syncthreads();
#pragma unroll
  for (int r = 0; r < 2; ++r) {  // scatter into bucket order
    int e = t + r * 1024;
    int b = sB[e];
    int slot = atomicAdd(&bcur[b], 1);
    Sp[slot] = sP[e];
    Sn[slot] = sN[e];
    Smeta[slot] = (b << 16) | e;
  }
  __syncthreads();
  if (t < 256) {  // per-bucket sums
    int s0 = bstart[t], s1 = s0 + cnt[t];
    float ap = 0.f, an = 0.f;
    for (int q = s0; q < s1; ++q) { ap += Sp[q]; an += Sn[q]; }
    bsP[t] = ap; bsN[t] = an;
  }
  __syncthreads();
  if (wv == 0) {  // bucket-level exclusive prefix(P) / suffix(N)
    int b4 = lane * 4;
    float p0 = bsP[b4], p1 = bsP[b4 + 1], p2 = bsP[b4 + 2], p3 = bsP[b4 + 3];
    float n0 = bsN[b4], n1 = bsN[b4 + 1], n2 = bsN[b4 + 2], n3 = bsN[b4 + 3];
    float tp = p0 + p1 + p2 + p3, tn = n0 + n1 + n2 + n3;
    float ip = tp, in_ = tn;
#pragma unroll
    for (int d = 1; d < 64; d <<= 1) {
      float yp = __shfl_up(ip, d);
      float yn = __shfl_up(in_, d);
      if (lane >= d) { ip += yp; in_ += yn; }
    }
    float totn = __shfl(in_, 63);
    float runp = ip - tp;
    float runn = in_ - tn;
    Pbel[b4] = runp; Nab[b4] = totn - runn - n0; runp += p0; runn += n0;
    Pbel[b4 + 1] = runp; Nab[b4 + 1] = totn - runn - n1; runp += p1; runn += n1;
    Pbel[b4 + 2] = runp; Nab[b4 + 2] = totn - runn - n2; runp += p2; runn += n2;
    Pbel[b4 + 3] = runp; Nab[b4 + 3] = totn - runn - n3;
  }
  __syncthreads();
#pragma unroll
  for (int r = 0; r < 2; ++r) {
    int s = t + r * 1024;
    int meta = Smeta[s];
    int b = meta >> 16;
    int idx = meta & 0xFFFF;
    float p = Sp[s], n = Sn[s];
    float acc = n * Pbel[b] + p * Nab[b];
    int q0 = bstart[b], q1 = q0 + cnt[b];
    for (int q = q0; q < q1; ++q) acc += fminf(p * Sn[q], n * Sp[q]);
    featsT[(long)f * 2048 + idx] = acc;
  }
}

// ---------- final part 2: out[i] += sum_f featsT[f][i] * Wf[256+f] ----------
__global__ __launch_bounds__(256) void k_final2(const float* __restrict__ featsT,
                                                const float* __restrict__ Wf,
                                                float* __restrict__ out) {
  int i = blockIdx.x * 256 + threadIdx.x;
  float s = 0.f;
#pragma unroll 4
  for (int f = 0; f < 100; ++f) s += featsT[(long)f * 2048 + i] * Wf[256 + f];
  out[i] += s;
}

extern "C" void kernel_launch(void* const* d_in, const int* in_sizes, int n_in,
                              void* d_out, int out_size, void* d_ws, size_t ws_size,
                              hipStream_t stream) {
  const float* x  = (const float*)d_in[0];
  const float* W1 = (const float*)d_in[1];
  const float* b1 = (const float*)d_in[2];
  const float* W2 = (const float*)d_in[3];
  const float* b2 = (const float*)d_in[4];
  const float* T  = (const float*)d_in[5];
  const float* Wf = (const float*)d_in[6];
  const float* bf = (const float*)d_in[7];
  float* out = (float*)d_out;

  char* w = (char*)d_ws;
  auto alloc = [&](size_t b) { char* p = w; w += (b + 255) & ~(size_t)255; return p; };
  __hip_bfloat16* xb  = (__hip_bfloat16*)alloc(2048L * 3072 * 2);  // 12 MB
  __hip_bfloat16* W1t = (__hip_bfloat16*)alloc(512L * 3072 * 2);   // 3 MB
  __hip_bfloat16* W2t = (__hip_bfloat16*)alloc(256L * 512 * 2);
  __hip_bfloat16* Tt  = (__hip_bfloat16*)alloc(128L * 256 * 2);
  __hip_bfloat16* h1b = (__hip_bfloat16*)alloc(2048L * 512 * 2);   // 2 MB
  __hip_bfloat16* h2b = (__hip_bfloat16*)alloc(2048L * 256 * 2);   // 1 MB
  float*          feT = (float*)alloc(100L * 2048 * 4);            // 0.8 MB
  float*          P1  = (float*)alloc(4L * 2048 * 512 * 4);        // 16 MB
  float*          P2  = (float*)alloc(2L * 2048 * 256 * 4);        // 4 MB
  float*          P3  = (float*)alloc(4L * 2048 * 128 * 4);        // 4 MB

  // prep: x->bf16 (6144) + W1t (1536) + W2t (128) + Tt (32)
  k_prep<<<7840, 256, 0, stream>>>(x, xb, W1, W1t, W2, W2t, T, Tt);
  // h1 = leakyrelu(x @ W1 + b1): 128x64 tile, split-K=4 (512 blocks, 2/CU)
  k_gemm1<<<dim3(16, 8, 4), 256, 0, stream>>>(xb, W1t, P1, 3072, 768);
  k_comb<4><<<1024, 256, 0, stream>>>(P1, b1, h1b, 262144, 511);
  // h2 = leakyrelu(h1 @ W2 + b2): split-K=2; combine fuses out[i] = h2.Wf + bf
  k_gemm<false><<<dim3(32, 4, 2), 256, 0, stream>>>(h1b, W2t, P2, 2048, 256, 512, 256, 256);
  k_comb2row<<<512, 256, 0, stream>>>(P2, b2, Wf, bf, h2b, out);
  // m = h2 @ T: split-K=4, transposed partial stores (mTz[128][2048] per z)
  k_gemm<true><<<dim3(32, 2, 4), 256, 0, stream>>>(h2b, Tt, P3, 2048, 128, 256, 64, 2048);
  // minibatch-discrimination features via value bucketing (O(B))
  k_bucketfeats<<<100, 1024, 0, stream>>>(P3, feT);
  // final part 2: add feats dot
  k_final2<<<8, 256, 0, stream>>>(feT, Wf, out);
}

// Round 3
// 135.782 us; speedup vs baseline: 1.2314x; 1.2314x over previous
//
#include <hip/hip_runtime.h>
#include <hip/hip_bf16.h>

#define LEAK 0.2f

typedef __attribute__((ext_vector_type(8))) short short8;
typedef __attribute__((ext_vector_type(4))) float f32x4;

// ---------- fused prep: x->bf16 convert ++ W1,W2,T transpose+convert ----------
// grid: [0,6144) convert, [6144,7680) W1t, [7680,7808) W2t, [7808,7840) Tt
__global__ __launch_bounds__(256) void k_prep(const float* __restrict__ x,
                                              __hip_bfloat16* __restrict__ xb,
                                              const float* __restrict__ W1,
                                              __hip_bfloat16* __restrict__ W1t,
                                              const float* __restrict__ W2,
                                              __hip_bfloat16* __restrict__ W2t,
                                              const float* __restrict__ T,
                                              __hip_bfloat16* __restrict__ Tt) {
  int b = blockIdx.x;
  int t = threadIdx.x;
  if (b < 6144) {
    int idx = b * 256 + t;
    float4 v = reinterpret_cast<const float4*>(x)[idx];
    union { ushort4 u; __hip_bfloat16 h[4]; } c;
    c.h[0] = __float2bfloat16(v.x);
    c.h[1] = __float2bfloat16(v.y);
    c.h[2] = __float2bfloat16(v.z);
    c.h[3] = __float2bfloat16(v.w);
    reinterpret_cast<ushort4*>(xb)[idx] = c.u;
    return;
  }
  __shared__ float tile[32][33];
  const float* W;
  __hip_bfloat16* Wt;
  int K, N, kblk, nblk;
  int b2 = b - 6144;
  if (b2 < 1536) {                  // W1: 3072x512 -> 512x3072
    W = W1; Wt = W1t; K = 3072; N = 512;
    kblk = b2 % 96; nblk = b2 / 96;
  } else if (b2 < 1664) {           // W2: 512x256 -> 256x512
    int b3 = b2 - 1536;
    W = W2; Wt = W2t; K = 512; N = 256;
    kblk = b3 % 16; nblk = b3 / 16;
  } else {                          // T: 256x100 -> 128x256 (zero-pad n>=100)
    int b4 = b2 - 1664;
    W = T; Wt = Tt; K = 256; N = 100;
    kblk = b4 % 8; nblk = b4 / 8;
  }
  int k0 = kblk * 32, n0 = nblk * 32;
  int tx = t & 31, ty = t >> 5;  // 32 x 8
#pragma unroll
  for (int r = 0; r < 4; ++r) {
    int n = n0 + tx;
    tile[ty + r * 8][tx] = (n < N) ? W[(long)(k0 + ty + r * 8) * N + n] : 0.f;
  }
  __syncthreads();
#pragma unroll
  for (int r = 0; r < 4; ++r)
    Wt[(long)(n0 + ty + r * 8) * K + k0 + tx] = __float2bfloat16(tile[tx][ty + r * 8]);
}

// ---------- bf16 MFMA GEMM, split-K, BK=64: Cp[z] = A[:,z*KSPL:+KSPL] @ Bt^T ----------
// A[M][K] bf16 row-major, Bt[N][K] bf16 row-major. Block tile 64x64, BK=64,
// 4 waves 2x2, wave 32x32 = 2x2 MFMA tiles of 16x16x32 (x2 k-halves).
// Register prefetch of next global tile overlaps MFMA+ds_read.
// TRANSP: store partial transposed (Cz[n][m], ld=ldO).
// NOTE (round-1/2 lesson): do NOT trade occupancy for per-wave density here —
// this problem is L2-resident and latency-bound; 64x64 @ 3 blocks/CU beats
// 128x64 @ 2 blocks/CU by ~4x (measured: 13us vs 51us for GEMM1).
template <bool TRANSP>
__global__ __launch_bounds__(256) void k_gemm(const __hip_bfloat16* __restrict__ A,
                                              const __hip_bfloat16* __restrict__ Bt,
                                              float* __restrict__ Cp,
                                              int M, int N, int K, int KSPL, int ldO) {
  __shared__ __align__(16) __hip_bfloat16 As[64][72];  // +8 pad (2-way max = free)
  __shared__ __align__(16) __hip_bfloat16 Bs[64][72];
  int tid = threadIdx.x;
  int lane = tid & 63;
  int wv = tid >> 6;
  int wm = wv & 1, wn = wv >> 1;
  int quad = lane >> 4, l16 = lane & 15;
  long m0 = (long)blockIdx.x * 64, n0 = (long)blockIdx.y * 64;
  int srow = tid >> 2, scol = (tid & 3) * 16;
  int kStart = blockIdx.z * KSPL;
  const __hip_bfloat16* Ag = A + (m0 + srow) * K + kStart + scol;
  const __hip_bfloat16* Bg = Bt + (n0 + srow) * K + kStart + scol;

  int4 ra0 = *reinterpret_cast<const int4*>(Ag);
  int4 ra1 = *reinterpret_cast<const int4*>(Ag + 8);
  int4 rb0 = *reinterpret_cast<const int4*>(Bg);
  int4 rb1 = *reinterpret_cast<const int4*>(Bg + 8);

  f32x4 acc[2][2] = {};
  for (int kb = 0; kb < KSPL; kb += 64) {
    *reinterpret_cast<int4*>(&As[srow][scol]) = ra0;
    *reinterpret_cast<int4*>(&As[srow][scol + 8]) = ra1;
    *reinterpret_cast<int4*>(&Bs[srow][scol]) = rb0;
    *reinterpret_cast<int4*>(&Bs[srow][scol + 8]) = rb1;
    __syncthreads();
    if (kb + 64 < KSPL) {
      ra0 = *reinterpret_cast<const int4*>(Ag + kb + 64);
      ra1 = *reinterpret_cast<const int4*>(Ag + kb + 72);
      rb0 = *reinterpret_cast<const int4*>(Bg + kb + 64);
      rb1 = *reinterpret_cast<const int4*>(Bg + kb + 72);
    }
#pragma unroll
    for (int half = 0; half < 2; ++half) {
      short8 af[2], bfr[2];
#pragma unroll
      for (int t = 0; t < 2; ++t) {
        af[t]  = *reinterpret_cast<const short8*>(&As[wm * 32 + t * 16 + l16][half * 32 + quad * 8]);
        bfr[t] = *reinterpret_cast<const short8*>(&Bs[wn * 32 + t * 16 + l16][half * 32 + quad * 8]);
      }
#pragma unroll
      for (int tm = 0; tm < 2; ++tm)
#pragma unroll
        for (int tn = 0; tn < 2; ++tn)
          acc[tm][tn] =
              __builtin_amdgcn_mfma_f32_16x16x32_bf16(af[tm], bfr[tn], acc[tm][tn], 0, 0, 0);
    }
    __syncthreads();
  }

  float* Cz = Cp + (long)blockIdx.z * M * N;
#pragma unroll
  for (int tm = 0; tm < 2; ++tm)
#pragma unroll
    for (int tn = 0; tn < 2; ++tn)
#pragma unroll
      for (int r = 0; r < 4; ++r) {
        long gm = m0 + wm * 32 + tm * 16 + quad * 4 + r;  // row = quad*4 + reg
        long gn = n0 + wn * 32 + tn * 16 + l16;           // col = lane&15
        if (TRANSP) Cz[gn * ldO + gm] = acc[tm][tn][r];
        else        Cz[gm * ldO + gn] = acc[tm][tn][r];
      }
}

// ---------- combine NZ partials + bias + leakyrelu -> bf16 (elementwise, h1) ----------
template <int NZ>
__global__ __launch_bounds__(256) void k_comb(const float* __restrict__ P,
                                              const float* __restrict__ bias,
                                              __hip_bfloat16* __restrict__ Ob,
                                              int total4, int nmask) {
  int idx = blockIdx.x * 256 + threadIdx.x;
  if (idx >= total4) return;
  float4 v = reinterpret_cast<const float4*>(P)[idx];
#pragma unroll
  for (int z = 1; z < NZ; ++z) {
    float4 a = reinterpret_cast<const float4*>(P + (long)z * total4 * 4)[idx];
    v.x += a.x; v.y += a.y; v.z += a.z; v.w += a.w;
  }
  int col = (idx * 4) & nmask;
  float4 bs = *reinterpret_cast<const float4*>(bias + col);
  v.x += bs.x; v.y += bs.y; v.z += bs.z; v.w += bs.w;
  v.x = v.x > 0.f ? v.x : LEAK * v.x;
  v.y = v.y > 0.f ? v.y : LEAK * v.y;
  v.z = v.z > 0.f ? v.z : LEAK * v.z;
  v.w = v.w > 0.f ? v.w : LEAK * v.w;
  union { ushort4 u; __hip_bfloat16 h[4]; } c;
  c.h[0] = __float2bfloat16(v.x);
  c.h[1] = __float2bfloat16(v.y);
  c.h[2] = __float2bfloat16(v.z);
  c.h[3] = __float2bfloat16(v.w);
  reinterpret_cast<ushort4*>(Ob)[idx] = c.u;
}

// ---------- h2 combine, wave-per-row: 2 partials + b2 + LReLU -> h2b bf16,
// plus fused final part 1: out[i] = h2[i,:].Wf[0:256] + bf  (feats added by k_final2) ----------
__global__ __launch_bounds__(256) void k_comb2row(const float* __restrict__ P,
                                                  const float* __restrict__ bias,
                                                  const float* __restrict__ Wf,
                                                  const float* __restrict__ bfp,
                                                  __hip_bfloat16* __restrict__ h2b,
                                                  float* __restrict__ out) {
  int wv = threadIdx.x >> 6, lane = threadIdx.x & 63;
  long i = (long)blockIdx.x * 4 + wv;
  long off = i * 256 + lane * 4;
  float4 v = *reinterpret_cast<const float4*>(P + off);
  float4 a = *reinterpret_cast<const float4*>(P + 2048L * 256 + off);
  v.x += a.x; v.y += a.y; v.z += a.z; v.w += a.w;
  float4 bs = *reinterpret_cast<const float4*>(bias + lane * 4);
  v.x += bs.x; v.y += bs.y; v.z += bs.z; v.w += bs.w;
  v.x = v.x > 0.f ? v.x : LEAK * v.x;
  v.y = v.y > 0.f ? v.y : LEAK * v.y;
  v.z = v.z > 0.f ? v.z : LEAK * v.z;
  v.w = v.w > 0.f ? v.w : LEAK * v.w;
  union { ushort4 u; __hip_bfloat16 h[4]; } c;
  c.h[0] = __float2bfloat16(v.x);
  c.h[1] = __float2bfloat16(v.y);
  c.h[2] = __float2bfloat16(v.z);
  c.h[3] = __float2bfloat16(v.w);
  reinterpret_cast<ushort4*>(h2b)[i * 64 + lane] = c.u;
  float4 wfv = *reinterpret_cast<const float4*>(Wf + lane * 4);
  float s = v.x * wfv.x + v.y * wfv.y + v.z * wfv.z + v.w * wfv.w;
#pragma unroll
  for (int d = 32; d; d >>= 1) s += __shfl_down(s, d);
  if (lane == 0) out[i] = s + bfp[0];
}

// ---------- bucketed minibatch-discrimination features, O(B) ----------
// feats[i] = sum_j e^{-|mi-mj|}. 256 value buckets: lower buckets contribute
// n_i*sum(p_j), upper p_i*sum(n_j) (exact by monotonicity), own bucket exact.
// p,n centered at mid, args clamped +-60 (clamp error < e^-70).
__global__ __launch_bounds__(1024) void k_bucketfeats(const float* __restrict__ mTz,
                                                      float* __restrict__ featsT) {
  __shared__ float sP[2048], sN[2048];
  __shared__ float Sp[2048], Sn[2048];
  __shared__ int Smeta[2048];
  __shared__ short sB[2048];
  __shared__ int cnt[256], bstart[256], bcur[256];
  __shared__ float bsP[256], bsN[256], Pbel[256], Nab[256];
  __shared__ float wred[32];
  __shared__ float sMin, sMax;
  int f = blockIdx.x;
  int t = threadIdx.x;
  int lane = t & 63, wv = t >> 6;
  const long FS = 2048L * 128;
  const float* row = mTz + (long)f * 2048;

  float m[2];
  float lmin = 3.4e38f, lmax = -3.4e38f;
#pragma unroll
  for (int r = 0; r < 2; ++r) {
    int e = t + r * 1024;
    float v = row[e] + row[FS + e] + row[2 * FS + e] + row[3 * FS + e];
    m[r] = v;
    lmin = fminf(lmin, v);
    lmax = fmaxf(lmax, v);
  }
#pragma unroll
  for (int d = 32; d; d >>= 1) {
    lmin = fminf(lmin, __shfl_down(lmin, d));
    lmax = fmaxf(lmax, __shfl_down(lmax, d));
  }
  if (lane == 0) { wred[wv] = lmin; wred[16 + wv] = lmax; }
  if (t < 256) cnt[t] = 0;
  __syncthreads();
  if (t == 0) {
    float a = wred[0], b = wred[16];
    for (int i = 1; i < 16; ++i) { a = fminf(a, wred[i]); b = fmaxf(b, wred[16 + i]); }
    sMin = a; sMax = b;
  }
  __syncthreads();
  float mn = sMin, mx = sMax;
  float rge = mx - mn;
  float scale = (rge > 1e-20f) ? 255.0f / rge : 0.f;
  float mid = 0.5f * (mn + mx);
#pragma unroll
  for (int r = 0; r < 2; ++r) {
    int e = t + r * 1024;
    float v = m[r];
    int b = (int)((v - mn) * scale);
    b = b < 255 ? b : 255;
    float arg = fminf(fmaxf(v - mid, -60.f), 60.f);
    sP[e] = __expf(arg);
    sN[e] = __expf(-arg);
    sB[e] = (short)b;
    atomicAdd(&cnt[b], 1);
  }
  __syncthreads();
  if (wv == 0) {  // exclusive prefix of cnt (4 bins/lane + wave scan)
    int b4 = lane * 4;
    int c0 = cnt[b4], c1 = cnt[b4 + 1], c2 = cnt[b4 + 2], c3 = cnt[b4 + 3];
    int tot = c0 + c1 + c2 + c3;
    int inc = tot;
#pragma unroll
    for (int d = 1; d < 64; d <<= 1) {
      int y = __shfl_up(inc, d);
      if (lane >= d) inc += y;
    }
    int run = inc - tot;
    bstart[b4] = run; bcur[b4] = run; run += c0;
    bstart[b4 + 1] = run; bcur[b4 + 1] = run; run += c1;
    bstart[b4 + 2] = run; bcur[b4 + 2] = run; run += c2;
    bstart[b4 + 3] = run; bcur[b4 + 3] = run;
  }
  __syncthreads();
#pragma unroll
  for (int r = 0; r < 2; ++r) {  // scatter into bucket order
    int e = t + r * 1024;
    int b = sB[e];
    int slot = atomicAdd(&bcur[b], 1);
    Sp[slot] = sP[e];
    Sn[slot] = sN[e];
    Smeta[slot] = (b << 16) | e;
  }
  __syncthreads();
  if (t < 256) {  // per-bucket sums
    int s0 = bstart[t], s1 = s0 + cnt[t];
    float ap = 0.f, an = 0.f;
    for (int q = s0; q < s1; ++q) { ap += Sp[q]; an += Sn[q]; }
    bsP[t] = ap; bsN[t] = an;
  }
  __syncthreads();
  if (wv == 0) {  // bucket-level exclusive prefix(P) / suffix(N)
    int b4 = lane * 4;
    float p0 = bsP[b4], p1 = bsP[b4 + 1], p2 = bsP[b4 + 2], p3 = bsP[b4 + 3];
    float n0 = bsN[b4], n1 = bsN[b4 + 1], n2 = bsN[b4 + 2], n3 = bsN[b4 + 3];
    float tp = p0 + p1 + p2 + p3, tn = n0 + n1 + n2 + n3;
    float ip = tp, in_ = tn;
#pragma unroll
    for (int d = 1; d < 64; d <<= 1) {
      float yp = __shfl_up(ip, d);
      float yn = __shfl_up(in_, d);
      if (lane >= d) { ip += yp; in_ += yn; }
    }
    float totn = __shfl(in_, 63);
    float runp = ip - tp;
    float runn = in_ - tn;
    Pbel[b4] = runp; Nab[b4] = totn - runn - n0; runp += p0; runn += n0;
    Pbel[b4 + 1] = runp; Nab[b4 + 1] = totn - runn - n1; runp += p1; runn += n1;
    Pbel[b4 + 2] = runp; Nab[b4 + 2] = totn - runn - n2; runp += p2; runn += n2;
    Pbel[b4 + 3] = runp; Nab[b4 + 3] = totn - runn - n3;
  }
  __syncthreads();
#pragma unroll
  for (int r = 0; r < 2; ++r) {
    int s = t + r * 1024;
    int meta = Smeta[s];
    int b = meta >> 16;
    int idx = meta & 0xFFFF;
    float p = Sp[s], n = Sn[s];
    float acc = n * Pbel[b] + p * Nab[b];
    int q0 = bstart[b], q1 = q0 + cnt[b];
    for (int q = q0; q < q1; ++q) acc += fminf(p * Sn[q], n * Sp[q]);
    featsT[(long)f * 2048 + idx] = acc;
  }
}

// ---------- final part 2: out[i] += sum_f featsT[f][i] * Wf[256+f] ----------
__global__ __launch_bounds__(256) void k_final2(const float* __restrict__ featsT,
                                                const float* __restrict__ Wf,
                                                float* __restrict__ out) {
  int i = blockIdx.x * 256 + threadIdx.x;
  float s = 0.f;
#pragma unroll 4
  for (int f = 0; f < 100; ++f) s += featsT[(long)f * 2048 + i] * Wf[256 + f];
  out[i] += s;
}

extern "C" void kernel_launch(void* const* d_in, const int* in_sizes, int n_in,
                              void* d_out, int out_size, void* d_ws, size_t ws_size,
                              hipStream_t stream) {
  const float* x  = (const float*)d_in[0];
  const float* W1 = (const float*)d_in[1];
  const float* b1 = (const float*)d_in[2];
  const float* W2 = (const float*)d_in[3];
  const float* b2 = (const float*)d_in[4];
  const float* T  = (const float*)d_in[5];
  const float* Wf = (const float*)d_in[6];
  const float* bf = (const float*)d_in[7];
  float* out = (float*)d_out;

  char* w = (char*)d_ws;
  auto alloc = [&](size_t b) { char* p = w; w += (b + 255) & ~(size_t)255; return p; };
  __hip_bfloat16* xb  = (__hip_bfloat16*)alloc(2048L * 3072 * 2);  // 12 MB
  __hip_bfloat16* W1t = (__hip_bfloat16*)alloc(512L * 3072 * 2);   // 3 MB
  __hip_bfloat16* W2t = (__hip_bfloat16*)alloc(256L * 512 * 2);
  __hip_bfloat16* Tt  = (__hip_bfloat16*)alloc(128L * 256 * 2);
  __hip_bfloat16* h1b = (__hip_bfloat16*)alloc(2048L * 512 * 2);   // 2 MB
  __hip_bfloat16* h2b = (__hip_bfloat16*)alloc(2048L * 256 * 2);   // 1 MB
  float*          feT = (float*)alloc(100L * 2048 * 4);            // 0.8 MB
  float*          P1  = (float*)alloc(3L * 2048 * 512 * 4);        // 12 MB
  float*          P2  = (float*)alloc(2L * 2048 * 256 * 4);        // 4 MB
  float*          P3  = (float*)alloc(4L * 2048 * 128 * 4);        // 4 MB

  // prep: x->bf16 (6144) + W1t (1536) + W2t (128) + Tt (32)
  k_prep<<<7840, 256, 0, stream>>>(x, xb, W1, W1t, W2, W2t, T, Tt);
  // h1 = leakyrelu(x @ W1 + b1): split-K=3 (768 blocks, 3/CU), BK=64
  k_gemm<false><<<dim3(32, 8, 3), 256, 0, stream>>>(xb, W1t, P1, 2048, 512, 3072, 1024, 512);
  k_comb<3><<<1024, 256, 0, stream>>>(P1, b1, h1b, 262144, 511);
  // h2 = leakyrelu(h1 @ W2 + b2): split-K=2; combine fuses out[i] = h2.Wf + bf
  k_gemm<false><<<dim3(32, 4, 2), 256, 0, stream>>>(h1b, W2t, P2, 2048, 256, 512, 256, 256);
  k_comb2row<<<512, 256, 0, stream>>>(P2, b2, Wf, bf, h2b, out);
  // m = h2 @ T: split-K=4, transposed partial stores (mTz[128][2048] per z)
  k_gemm<true><<<dim3(32, 2, 4), 256, 0, stream>>>(h2b, Tt, P3, 2048, 128, 256, 64, 2048);
  // minibatch-discrimination features via value bucketing (O(B))
  k_bucketfeats<<<100, 1024, 0, stream>>>(P3, feT);
  // final part 2: add feats dot
  k_final2<<<8, 256, 0, stream>>>(feT, Wf, out);
}

// Round 4
// 126.190 us; speedup vs baseline: 1.3250x; 1.0760x over previous
//
#include <hip/hip_runtime.h>
#include <hip/hip_bf16.h>

#define LEAK 0.2f

typedef __attribute__((ext_vector_type(8))) short short8;
typedef __attribute__((ext_vector_type(4))) float f32x4;

// NOTE (session accounting): dur_us includes two ~43us fillBufferAligned
// workspace re-poison dispatches (256 MiB each) issued by the harness —
// ~86us is a fixed floor. Controllable kernel budget is ~43us at round-0.

// ---------- fused prep: x->bf16 convert ++ W1,W2,T transpose+convert ----------
// grid: [0,6144) convert, [6144,7680) W1t, [7680,7808) W2t, [7808,7840) Tt
__global__ __launch_bounds__(256) void k_prep(const float* __restrict__ x,
                                              __hip_bfloat16* __restrict__ xb,
                                              const float* __restrict__ W1,
                                              __hip_bfloat16* __restrict__ W1t,
                                              const float* __restrict__ W2,
                                              __hip_bfloat16* __restrict__ W2t,
                                              const float* __restrict__ T,
                                              __hip_bfloat16* __restrict__ Tt) {
  int b = blockIdx.x;
  int t = threadIdx.x;
  if (b < 6144) {
    int idx = b * 256 + t;
    float4 v = reinterpret_cast<const float4*>(x)[idx];
    union { ushort4 u; __hip_bfloat16 h[4]; } c;
    c.h[0] = __float2bfloat16(v.x);
    c.h[1] = __float2bfloat16(v.y);
    c.h[2] = __float2bfloat16(v.z);
    c.h[3] = __float2bfloat16(v.w);
    reinterpret_cast<ushort4*>(xb)[idx] = c.u;
    return;
  }
  __shared__ float tile[32][33];
  const float* W;
  __hip_bfloat16* Wt;
  int K, N, kblk, nblk;
  int b2 = b - 6144;
  if (b2 < 1536) {                  // W1: 3072x512 -> 512x3072
    W = W1; Wt = W1t; K = 3072; N = 512;
    kblk = b2 % 96; nblk = b2 / 96;
  } else if (b2 < 1664) {           // W2: 512x256 -> 256x512
    int b3 = b2 - 1536;
    W = W2; Wt = W2t; K = 512; N = 256;
    kblk = b3 % 16; nblk = b3 / 16;
  } else {                          // T: 256x100 -> 128x256 (zero-pad n>=100)
    int b4 = b2 - 1664;
    W = T; Wt = Tt; K = 256; N = 100;
    kblk = b4 % 8; nblk = b4 / 8;
  }
  int k0 = kblk * 32, n0 = nblk * 32;
  int tx = t & 31, ty = t >> 5;  // 32 x 8
#pragma unroll
  for (int r = 0; r < 4; ++r) {
    int n = n0 + tx;
    tile[ty + r * 8][tx] = (n < N) ? W[(long)(k0 + ty + r * 8) * N + n] : 0.f;
  }
  __syncthreads();
#pragma unroll
  for (int r = 0; r < 4; ++r)
    Wt[(long)(n0 + ty + r * 8) * K + k0 + tx] = __float2bfloat16(tile[tx][ty + r * 8]);
}

// ---------- bf16 MFMA GEMM, split-K, BK=64: Cp[z] = A[:,z*KSPL:+KSPL] @ Bt^T ----------
// A[M][K] bf16 row-major, Bt[N][K] bf16 row-major. Block tile 64x64, BK=64,
// 4 waves 2x2, wave 32x32 = 2x2 MFMA tiles of 16x16x32 (x2 k-halves).
// Register prefetch of next global tile overlaps MFMA+ds_read.
// TRANSP: store partial transposed (Cz[n][m], ld=ldO). BF16OUT: partials as bf16.
// NOTE (round-1/2 lesson): do NOT trade occupancy for per-wave density here —
// this problem is L2-resident and latency-bound; 64x64 @ 3 blocks/CU beats
// 128x64 @ 2 blocks/CU by ~4x (measured: 13us vs 51us for GEMM1), and a
// 2-phase global_load_lds pipeline at this depth regresses (round-1).
template <bool TRANSP, bool BF16OUT>
__global__ __launch_bounds__(256) void k_gemm(const __hip_bfloat16* __restrict__ A,
                                              const __hip_bfloat16* __restrict__ Bt,
                                              float* __restrict__ Cp,
                                              int M, int N, int K, int KSPL, int ldO) {
  __shared__ __align__(16) __hip_bfloat16 As[64][72];  // +8 pad (2-way max = free)
  __shared__ __align__(16) __hip_bfloat16 Bs[64][72];
  int tid = threadIdx.x;
  int lane = tid & 63;
  int wv = tid >> 6;
  int wm = wv & 1, wn = wv >> 1;
  int quad = lane >> 4, l16 = lane & 15;
  long m0 = (long)blockIdx.x * 64, n0 = (long)blockIdx.y * 64;
  int srow = tid >> 2, scol = (tid & 3) * 16;
  int kStart = blockIdx.z * KSPL;
  const __hip_bfloat16* Ag = A + (m0 + srow) * K + kStart + scol;
  const __hip_bfloat16* Bg = Bt + (n0 + srow) * K + kStart + scol;

  int4 ra0 = *reinterpret_cast<const int4*>(Ag);
  int4 ra1 = *reinterpret_cast<const int4*>(Ag + 8);
  int4 rb0 = *reinterpret_cast<const int4*>(Bg);
  int4 rb1 = *reinterpret_cast<const int4*>(Bg + 8);

  f32x4 acc[2][2] = {};
  for (int kb = 0; kb < KSPL; kb += 64) {
    *reinterpret_cast<int4*>(&As[srow][scol]) = ra0;
    *reinterpret_cast<int4*>(&As[srow][scol + 8]) = ra1;
    *reinterpret_cast<int4*>(&Bs[srow][scol]) = rb0;
    *reinterpret_cast<int4*>(&Bs[srow][scol + 8]) = rb1;
    __syncthreads();
    if (kb + 64 < KSPL) {
      ra0 = *reinterpret_cast<const int4*>(Ag + kb + 64);
      ra1 = *reinterpret_cast<const int4*>(Ag + kb + 72);
      rb0 = *reinterpret_cast<const int4*>(Bg + kb + 64);
      rb1 = *reinterpret_cast<const int4*>(Bg + kb + 72);
    }
#pragma unroll
    for (int half = 0; half < 2; ++half) {
      short8 af[2], bfr[2];
#pragma unroll
      for (int t = 0; t < 2; ++t) {
        af[t]  = *reinterpret_cast<const short8*>(&As[wm * 32 + t * 16 + l16][half * 32 + quad * 8]);
        bfr[t] = *reinterpret_cast<const short8*>(&Bs[wn * 32 + t * 16 + l16][half * 32 + quad * 8]);
      }
#pragma unroll
      for (int tm = 0; tm < 2; ++tm)
#pragma unroll
        for (int tn = 0; tn < 2; ++tn)
          acc[tm][tn] =
              __builtin_amdgcn_mfma_f32_16x16x32_bf16(af[tm], bfr[tn], acc[tm][tn], 0, 0, 0);
    }
    __syncthreads();
  }

#pragma unroll
  for (int tm = 0; tm < 2; ++tm)
#pragma unroll
    for (int tn = 0; tn < 2; ++tn)
#pragma unroll
      for (int r = 0; r < 4; ++r) {
        long gm = m0 + wm * 32 + tm * 16 + quad * 4 + r;  // row = quad*4 + reg
        long gn = n0 + wn * 32 + tn * 16 + l16;           // col = lane&15
        long off = TRANSP ? (gn * ldO + gm) : (gm * ldO + gn);
        if constexpr (BF16OUT) {
          __hip_bfloat16* Cz = reinterpret_cast<__hip_bfloat16*>(Cp) + (long)blockIdx.z * M * N;
          Cz[off] = __float2bfloat16(acc[tm][tn][r]);
        } else {
          float* Cz = Cp + (long)blockIdx.z * M * N;
          Cz[off] = acc[tm][tn][r];
        }
      }
}

// ---------- combine 3 bf16 partials + bias + leakyrelu -> bf16 (h1 path) ----------
// 8 elems/thread (16B loads). total8 = M*N/8.
__global__ __launch_bounds__(256) void k_comb_bf3(const __hip_bfloat16* __restrict__ P,
                                                  const float* __restrict__ bias,
                                                  __hip_bfloat16* __restrict__ Ob,
                                                  int total8, int nmask) {
  int idx = blockIdx.x * 256 + threadIdx.x;
  if (idx >= total8) return;
  union u8 { short8 v; ushort u[8]; };
  u8 a, b, c, o;
  a.v = reinterpret_cast<const short8*>(P)[idx];
  b.v = reinterpret_cast<const short8*>(P + (long)total8 * 8)[idx];
  c.v = reinterpret_cast<const short8*>(P + (long)total8 * 16)[idx];
  int col = (idx * 8) & nmask;
  float4 b0 = *reinterpret_cast<const float4*>(bias + col);
  float4 b1 = *reinterpret_cast<const float4*>(bias + col + 4);
  float bs[8] = {b0.x, b0.y, b0.z, b0.w, b1.x, b1.y, b1.z, b1.w};
#pragma unroll
  for (int j = 0; j < 8; ++j) {
    union { ushort u; __hip_bfloat16 h; } ca, cb, cc;
    ca.u = a.u[j]; cb.u = b.u[j]; cc.u = c.u[j];
    float v = __bfloat162float(ca.h) + __bfloat162float(cb.h) + __bfloat162float(cc.h) + bs[j];
    v = v > 0.f ? v : LEAK * v;
    union { ushort u; __hip_bfloat16 h; } co;
    co.h = __float2bfloat16(v);
    o.u[j] = co.u;
  }
  reinterpret_cast<short8*>(Ob)[idx] = o.v;
}

// ---------- h2 combine, wave-per-row: 2 partials + b2 + LReLU -> h2b bf16,
// plus fused final part 1: out[i] = h2[i,:].Wf[0:256] + bf  (feats added by k_final) ----------
__global__ __launch_bounds__(256) void k_comb2row(const float* __restrict__ P,
                                                  const float* __restrict__ bias,
                                                  const float* __restrict__ Wf,
                                                  const float* __restrict__ bfp,
                                                  __hip_bfloat16* __restrict__ h2b,
                                                  float* __restrict__ out) {
  int wv = threadIdx.x >> 6, lane = threadIdx.x & 63;
  long i = (long)blockIdx.x * 4 + wv;
  long off = i * 256 + lane * 4;
  float4 v = *reinterpret_cast<const float4*>(P + off);
  float4 a = *reinterpret_cast<const float4*>(P + 2048L * 256 + off);
  v.x += a.x; v.y += a.y; v.z += a.z; v.w += a.w;
  float4 bs = *reinterpret_cast<const float4*>(bias + lane * 4);
  v.x += bs.x; v.y += bs.y; v.z += bs.z; v.w += bs.w;
  v.x = v.x > 0.f ? v.x : LEAK * v.x;
  v.y = v.y > 0.f ? v.y : LEAK * v.y;
  v.z = v.z > 0.f ? v.z : LEAK * v.z;
  v.w = v.w > 0.f ? v.w : LEAK * v.w;
  union { ushort4 u; __hip_bfloat16 h[4]; } c;
  c.h[0] = __float2bfloat16(v.x);
  c.h[1] = __float2bfloat16(v.y);
  c.h[2] = __float2bfloat16(v.z);
  c.h[3] = __float2bfloat16(v.w);
  reinterpret_cast<ushort4*>(h2b)[i * 64 + lane] = c.u;
  float4 wfv = *reinterpret_cast<const float4*>(Wf + lane * 4);
  float s = v.x * wfv.x + v.y * wfv.y + v.z * wfv.z + v.w * wfv.w;
#pragma unroll
  for (int d = 32; d; d >>= 1) s += __shfl_down(s, d);
  if (lane == 0) out[i] = s + bfp[0];
}

// ---------- bucketed minibatch-discrimination features, O(B) ----------
// feats[i] = sum_j e^{-|mi-mj|}. 256 value buckets: lower buckets contribute
// n_i*sum(p_j), upper p_i*sum(n_j) (exact by monotonicity), own bucket exact.
// p,n centered at mid, args clamped +-60 (clamp error < e^-70).
__global__ __launch_bounds__(1024) void k_bucketfeats(const float* __restrict__ mTz,
                                                      float* __restrict__ featsT) {
  __shared__ float sP[2048], sN[2048];
  __shared__ float Sp[2048], Sn[2048];
  __shared__ int Smeta[2048];
  __shared__ short sB[2048];
  __shared__ int cnt[256], bstart[256], bcur[256];
  __shared__ float bsP[256], bsN[256], Pbel[256], Nab[256];
  __shared__ float wred[32];
  __shared__ float sMin, sMax;
  int f = blockIdx.x;
  int t = threadIdx.x;
  int lane = t & 63, wv = t >> 6;
  const long FS = 2048L * 128;
  const float* row = mTz + (long)f * 2048;

  float m[2];
  float lmin = 3.4e38f, lmax = -3.4e38f;
#pragma unroll
  for (int r = 0; r < 2; ++r) {
    int e = t + r * 1024;
    float v = row[e] + row[FS + e] + row[2 * FS + e] + row[3 * FS + e];
    m[r] = v;
    lmin = fminf(lmin, v);
    lmax = fmaxf(lmax, v);
  }
#pragma unroll
  for (int d = 32; d; d >>= 1) {
    lmin = fminf(lmin, __shfl_down(lmin, d));
    lmax = fmaxf(lmax, __shfl_down(lmax, d));
  }
  if (lane == 0) { wred[wv] = lmin; wred[16 + wv] = lmax; }
  if (t < 256) cnt[t] = 0;
  __syncthreads();
  if (t == 0) {
    float a = wred[0], b = wred[16];
    for (int i = 1; i < 16; ++i) { a = fminf(a, wred[i]); b = fmaxf(b, wred[16 + i]); }
    sMin = a; sMax = b;
  }
  __syncthreads();
  float mn = sMin, mx = sMax;
  float rge = mx - mn;
  float scale = (rge > 1e-20f) ? 255.0f / rge : 0.f;
  float mid = 0.5f * (mn + mx);
#pragma unroll
  for (int r = 0; r < 2; ++r) {
    int e = t + r * 1024;
    float v = m[r];
    int b = (int)((v - mn) * scale);
    b = b < 255 ? b : 255;
    float arg = fminf(fmaxf(v - mid, -60.f), 60.f);
    sP[e] = __expf(arg);
    sN[e] = __expf(-arg);
    sB[e] = (short)b;
    atomicAdd(&cnt[b], 1);
  }
  __syncthreads();
  if (wv == 0) {  // exclusive prefix of cnt (4 bins/lane + wave scan)
    int b4 = lane * 4;
    int c0 = cnt[b4], c1 = cnt[b4 + 1], c2 = cnt[b4 + 2], c3 = cnt[b4 + 3];
    int tot = c0 + c1 + c2 + c3;
    int inc = tot;
#pragma unroll
    for (int d = 1; d < 64; d <<= 1) {
      int y = __shfl_up(inc, d);
      if (lane >= d) inc += y;
    }
    int run = inc - tot;
    bstart[b4] = run; bcur[b4] = run; run += c0;
    bstart[b4 + 1] = run; bcur[b4 + 1] = run; run += c1;
    bstart[b4 + 2] = run; bcur[b4 + 2] = run; run += c2;
    bstart[b4 + 3] = run; bcur[b4 + 3] = run;
  }
  __syncthreads();
#pragma unroll
  for (int r = 0; r < 2; ++r) {  // scatter into bucket order
    int e = t + r * 1024;
    int b = sB[e];
    int slot = atomicAdd(&bcur[b], 1);
    Sp[slot] = sP[e];
    Sn[slot] = sN[e];
    Smeta[slot] = (b << 16) | e;
  }
  __syncthreads();
  if (t < 256) {  // per-bucket sums
    int s0 = bstart[t], s1 = s0 + cnt[t];
    float ap = 0.f, an = 0.f;
    for (int q = s0; q < s1; ++q) { ap += Sp[q]; an += Sn[q]; }
    bsP[t] = ap; bsN[t] = an;
  }
  __syncthreads();
  if (wv == 0) {  // bucket-level exclusive prefix(P) / suffix(N)
    int b4 = lane * 4;
    float p0 = bsP[b4], p1 = bsP[b4 + 1], p2 = bsP[b4 + 2], p3 = bsP[b4 + 3];
    float n0 = bsN[b4], n1 = bsN[b4 + 1], n2 = bsN[b4 + 2], n3 = bsN[b4 + 3];
    float tp = p0 + p1 + p2 + p3, tn = n0 + n1 + n2 + n3;
    float ip = tp, in_ = tn;
#pragma unroll
    for (int d = 1; d < 64; d <<= 1) {
      float yp = __shfl_up(ip, d);
      float yn = __shfl_up(in_, d);
      if (lane >= d) { ip += yp; in_ += yn; }
    }
    float totn = __shfl(in_, 63);
    float runp = ip - tp;
    float runn = in_ - tn;
    Pbel[b4] = runp; Nab[b4] = totn - runn - n0; runp += p0; runn += n0;
    Pbel[b4 + 1] = runp; Nab[b4 + 1] = totn - runn - n1; runp += p1; runn += n1;
    Pbel[b4 + 2] = runp; Nab[b4 + 2] = totn - runn - n2; runp += p2; runn += n2;
    Pbel[b4 + 3] = runp; Nab[b4 + 3] = totn - runn - n3;
  }
  __syncthreads();
#pragma unroll
  for (int r = 0; r < 2; ++r) {
    int s = t + r * 1024;
    int meta = Smeta[s];
    int b = meta >> 16;
    int idx = meta & 0xFFFF;
    float p = Sp[s], n = Sn[s];
    float acc = n * Pbel[b] + p * Nab[b];
    int q0 = bstart[b], q1 = q0 + cnt[b];
    for (int q = q0; q < q1; ++q) acc += fminf(p * Sn[q], n * Sp[q]);
    featsT[(long)f * 2048 + idx] = acc;
  }
}

// ---------- final part 2 (parallel, round-0 structure): out[i] += feats.Wf ----------
// 512 blocks x 4 waves: wave wv owns row i; lanes cover features (f=lane, lane+64).
__global__ __launch_bounds__(256) void k_final(const float* __restrict__ featsT,
                                               const float* __restrict__ Wf,
                                               float* __restrict__ out) {
  int wv = threadIdx.x >> 6, lane = threadIdx.x & 63;
  long i = (long)blockIdx.x * 4 + wv;
  float s = 0.f;
  for (int f = lane; f < 100; f += 64) s += featsT[(long)f * 2048 + i] * Wf[256 + f];
#pragma unroll
  for (int off = 32; off; off >>= 1) s += __shfl_down(s, off);
  if (lane == 0) out[i] += s;
}

extern "C" void kernel_launch(void* const* d_in, const int* in_sizes, int n_in,
                              void* d_out, int out_size, void* d_ws, size_t ws_size,
                              hipStream_t stream) {
  const float* x  = (const float*)d_in[0];
  const float* W1 = (const float*)d_in[1];
  const float* b1 = (const float*)d_in[2];
  const float* W2 = (const float*)d_in[3];
  const float* b2 = (const float*)d_in[4];
  const float* T  = (const float*)d_in[5];
  const float* Wf = (const float*)d_in[6];
  const float* bf = (const float*)d_in[7];
  float* out = (float*)d_out;

  char* w = (char*)d_ws;
  auto alloc = [&](size_t b) { char* p = w; w += (b + 255) & ~(size_t)255; return p; };
  __hip_bfloat16* xb  = (__hip_bfloat16*)alloc(2048L * 3072 * 2);  // 12 MB
  __hip_bfloat16* W1t = (__hip_bfloat16*)alloc(512L * 3072 * 2);   // 3 MB
  __hip_bfloat16* W2t = (__hip_bfloat16*)alloc(256L * 512 * 2);
  __hip_bfloat16* Tt  = (__hip_bfloat16*)alloc(128L * 256 * 2);
  __hip_bfloat16* h1b = (__hip_bfloat16*)alloc(2048L * 512 * 2);   // 2 MB
  __hip_bfloat16* h2b = (__hip_bfloat16*)alloc(2048L * 256 * 2);   // 1 MB
  float*          feT = (float*)alloc(100L * 2048 * 4);            // 0.8 MB
  __hip_bfloat16* P1  = (__hip_bfloat16*)alloc(3L * 2048 * 512 * 2); // 6 MB (bf16 partials)
  float*          P2  = (float*)alloc(2L * 2048 * 256 * 4);        // 4 MB
  float*          P3  = (float*)alloc(4L * 2048 * 128 * 4);        // 4 MB

  // prep: x->bf16 (6144) + W1t (1536) + W2t (128) + Tt (32)
  k_prep<<<7840, 256, 0, stream>>>(x, xb, W1, W1t, W2, W2t, T, Tt);
  // h1 = leakyrelu(x @ W1 + b1): split-K=3 (768 blocks, 3/CU), BK=64, bf16 partials
  k_gemm<false, true><<<dim3(32, 8, 3), 256, 0, stream>>>(xb, W1t, (float*)P1, 2048, 512, 3072, 1024, 512);
  k_comb_bf3<<<512, 256, 0, stream>>>(P1, b1, h1b, 131072, 511);
  // h2 = leakyrelu(h1 @ W2 + b2): split-K=2; combine fuses out[i] = h2.Wf + bf
  k_gemm<false, false><<<dim3(32, 4, 2), 256, 0, stream>>>(h1b, W2t, P2, 2048, 256, 512, 256, 256);
  k_comb2row<<<512, 256, 0, stream>>>(P2, b2, Wf, bf, h2b, out);
  // m = h2 @ T: split-K=4, transposed partial stores (mTz[128][2048] per z)
  k_gemm<true, false><<<dim3(32, 2, 4), 256, 0, stream>>>(h2b, Tt, P3, 2048, 128, 256, 64, 2048);
  // minibatch-discrimination features via value bucketing (O(B))
  k_bucketfeats<<<100, 1024, 0, stream>>>(P3, feT);
  // final part 2: add feats dot (parallel wave-per-row)
  k_final<<<512, 256, 0, stream>>>(feT, Wf, out);
}